// Round 4
// baseline (85.552 us; speedup 1.0000x reference)
//
#include <hip/hip_runtime.h>
#include <stdint.h>
#include <stddef.h>

#define BATCH 256
#define IN_F  4096
#define OUT_F 4096
#define KSPLIT 4

typedef __attribute__((ext_vector_type(8))) short    bf16x8;
typedef __attribute__((ext_vector_type(4))) float    f32x4;
typedef __attribute__((ext_vector_type(2))) uint32_t u32x2;
typedef __attribute__((ext_vector_type(4))) uint32_t u32x4;

#define MFMA(a,b,c) __builtin_amdgcn_mfma_f32_16x16x32_bf16((a),(b),(c),0,0,0)
#define HALF_LOG2E 0.7213475204444817f   // exp(0.5*x) == exp2(x*HALF_LOG2E)

__device__ __forceinline__ uint32_t pack2bf(float a, float b) {
  uint32_t ua = __builtin_bit_cast(uint32_t, a);
  uint32_t ub = __builtin_bit_cast(uint32_t, b);
  ua += 0x7FFFu + ((ua >> 16) & 1u);
  ub += 0x7FFFu + ((ub >> 16) & 1u);
  return (ua >> 16) | (ub & 0xFFFF0000u);
}

__device__ __forceinline__ bf16x8 cvt8(const float* p) {
  f32x4 v0 = *(const f32x4*)p;
  f32x4 v1 = *(const f32x4*)(p + 4);
  union { u32x4 u; bf16x8 h; } r;
  r.u[0] = pack2bf(v0[0], v0[1]); r.u[1] = pack2bf(v0[2], v0[3]);
  r.u[2] = pack2bf(v1[0], v1[1]); r.u[3] = pack2bf(v1[2], v1[3]);
  return r.h;
}

__device__ __forceinline__ void gload_lds16(const void* g, void* l) {
  __builtin_amdgcn_global_load_lds(
      (const __attribute__((address_space(1))) uint32_t*)g,
      (__attribute__((address_space(3))) uint32_t*)l, 16, 0, 0);
}

// ---------------------------------------------------------------------------
// Prep: x fp32 -> bf16 (L2-resident during GEMM); bias = bmu + beps*exp(.5*blv)
// ---------------------------------------------------------------------------
__global__ __launch_bounds__(256) void prep_kernel(
    const float* __restrict__ x,
    const float* __restrict__ bmu,
    const float* __restrict__ blv,
    const float* __restrict__ beps,
    u32x4* __restrict__ xs4,
    float* __restrict__ bias)
{
  const uint32_t b = blockIdx.x;
  if (b < 512u) {
    const uint32_t c = b * 256u + threadIdx.x;
    const float* p = x + (size_t)c * 8u;
    f32x4 v0 = *(const f32x4*)p;
    f32x4 v1 = *(const f32x4*)(p + 4);
    u32x4 o;
    o[0] = pack2bf(v0[0], v0[1]); o[1] = pack2bf(v0[2], v0[3]);
    o[2] = pack2bf(v1[0], v1[1]); o[3] = pack2bf(v1[2], v1[3]);
    xs4[c] = o;
  } else {
    const uint32_t i = (b - 512u) * 256u + threadIdx.x;
    bias[i] = fmaf(beps[i], exp2f(blv[i] * HALF_LOG2E), bmu[i]);
  }
}

// ---------------------------------------------------------------------------
// Pass 1: stream-convert W = mu + eps*exp(.5*lv) -> bf16 tile images.
// Image (nt, kt): 4096 B = 16 rows x 256 B; within row r, 16B-group g
// stored at ((g ^ r) & 15) * 16 (XOR swizzle baked in -> conflict-free
// ds_read_b128 in pass 2). Thread: 8 consecutive k of one row: reads
// 3 x 32 B lane-linear, writes one 16 B group (16-lane groups cover a
// contiguous 256 B row-segment). No LDS, no barriers, 8192 WGs.
// ---------------------------------------------------------------------------
__global__ __launch_bounds__(256) void wcvt_kernel(
    const float* __restrict__ wmu,
    const float* __restrict__ wlv,
    const float* __restrict__ weps,
    uint8_t* __restrict__ wimg)
{
  const uint32_t c = blockIdx.x * 256u + threadIdx.x;  // 0 .. 2M-1
  const uint32_t n = c >> 9;          // W row
  const uint32_t q = c & 511u;        // 8k-chunk within row
  const size_t  off = ((size_t)n << 12) + (q << 3);
  f32x4 m0 = *(const f32x4*)(wmu + off);
  f32x4 m1 = *(const f32x4*)(wmu + off + 4);
  f32x4 v0 = *(const f32x4*)(wlv + off);
  f32x4 v1 = *(const f32x4*)(wlv + off + 4);
  f32x4 e0 = *(const f32x4*)(weps + off);
  f32x4 e1 = *(const f32x4*)(weps + off + 4);
  u32x4 o;
  o[0] = pack2bf(fmaf(e0[0], exp2f(v0[0] * HALF_LOG2E), m0[0]),
                 fmaf(e0[1], exp2f(v0[1] * HALF_LOG2E), m0[1]));
  o[1] = pack2bf(fmaf(e0[2], exp2f(v0[2] * HALF_LOG2E), m0[2]),
                 fmaf(e0[3], exp2f(v0[3] * HALF_LOG2E), m0[3]));
  o[2] = pack2bf(fmaf(e1[0], exp2f(v1[0] * HALF_LOG2E), m1[0]),
                 fmaf(e1[1], exp2f(v1[1] * HALF_LOG2E), m1[1]));
  o[3] = pack2bf(fmaf(e1[2], exp2f(v1[2] * HALF_LOG2E), m1[2]),
                 fmaf(e1[3], exp2f(v1[3] * HALF_LOG2E), m1[3]));
  const uint32_t nt = n >> 4, r = n & 15u, kt = q >> 4, g = q & 15u;
  *(u32x4*)(wimg + (((size_t)(nt * 32u + kt)) << 12)
                 + (r << 8) + (((g ^ r) & 15u) << 4)) = o;
}

// ---------------------------------------------------------------------------
// Pass 2: y = xs @ W_bf16^T (+ bias if NSPLIT==1, else fp32 partials).
// WG = 4 waves, BN=32 (2 n-tiles), BM=256, K-chunk = 4096/NSPLIT.
// Per iter: stage 2 tile images (8 KB, 1-KB-linear DMA chunks), sync,
// 32 MFMA with swizzled ds_reads (2-way bank = free), sync.
// ---------------------------------------------------------------------------
template<int NSPLIT>
__global__ __launch_bounds__(256, 2)
void vgemm_img(const uint16_t* __restrict__ xs,
               const uint8_t*  __restrict__ wimg,
               const float*    __restrict__ biasp,
               float*          __restrict__ out)
{
  __shared__ __align__(16) uint8_t lds[16384];   // 2 bufs x 2 images x 4 KB

  const int tid = threadIdx.x;
  const int wv  = tid >> 6;
  const int l   = tid & 63;
  const int cg  = blockIdx.x / NSPLIT;       // column group (32 cols)
  const int ks  = blockIdx.x % NSPLIT;
  const int nt0 = cg * 2;
  const int KT0 = ks * (32 / NSPLIT);        // first global k-tile
  const int NIT = 32 / NSPLIT;               // tiles in this k-chunk

  const int br = l & 15;                     // B row = output col offset
  const int kb = l >> 4;                     // k-octet 0..3
  const int arow0 = wv * 64 + br;

  f32x4 acc0[4] = {{0,0,0,0},{0,0,0,0},{0,0,0,0},{0,0,0,0}};
  f32x4 acc1[4] = {{0,0,0,0},{0,0,0,0},{0,0,0,0},{0,0,0,0}};

  auto STAGE = [&](int t, int buf) {
    const int kt = KT0 + t;
#pragma unroll
    for (int j = 0; j < 2; ++j) {
      const int ch = wv * 2 + j;             // 0..7 : 1 KB chunks
      const int i  = ch >> 2;                // image 0/1
      const int q  = ch & 3;                 // quarter
      const uint8_t* src = wimg + (((size_t)((nt0 + i) * 32 + kt)) << 12)
                                + q * 1024 + l * 16;
      gload_lds16(src, &lds[0] + buf * 8192 + i * 4096 + q * 1024 + l * 16);
    }
  };

  auto COMP = [&](int t, int buf) {
    const uint8_t* B = &lds[0] + buf * 8192;
#pragma unroll
    for (int s = 0; s < 4; ++s) {
      const int swz = br * 256 + ((((s * 4 + kb) ^ br) & 15) << 4);
      bf16x8 b0 = *(const bf16x8*)(B + swz);
      bf16x8 b1 = *(const bf16x8*)(B + 4096 + swz);
      const size_t kk = (size_t)(KT0 + t) * 128 + s * 32 + kb * 8;
#pragma unroll
      for (int j = 0; j < 4; ++j) {
        bf16x8 a = *(const bf16x8*)(xs + (size_t)(arow0 + 16 * j) * IN_F + kk);
        acc0[j] = MFMA(a, b0, acc0[j]);
        acc1[j] = MFMA(a, b1, acc1[j]);
      }
    }
  };

  STAGE(0, 0);
  for (int t = 0; t < NIT; ++t) {
    if (t + 1 < NIT) STAGE(t + 1, (t + 1) & 1);
    __syncthreads();                 // tile t (and t+1's DMA) landed
    COMP(t, t & 1);
    __syncthreads();                 // buf t&1 free for reuse
  }

  // ---- epilogue: D[row=(l>>4)*4+i][col=l&15] (validated R1-R3)
#pragma unroll
  for (int img = 0; img < 2; ++img) {
    const f32x4* acc = img ? acc1 : acc0;
    const int col = cg * 32 + img * 16 + br;
    if constexpr (NSPLIT == 1) {
      const float bv = biasp[col];
#pragma unroll
      for (int j = 0; j < 4; ++j) {
        const int rbase = wv * 64 + j * 16 + kb * 4;
#pragma unroll
        for (int i = 0; i < 4; ++i)
          out[(size_t)(rbase + i) * OUT_F + col] = acc[j][i] + bv;
      }
    } else {
      float* po = out + (size_t)ks * BATCH * OUT_F;
#pragma unroll
      for (int j = 0; j < 4; ++j) {
        const int rbase = wv * 64 + j * 16 + kb * 4;
#pragma unroll
        for (int i = 0; i < 4; ++i)
          po[(size_t)(rbase + i) * OUT_F + col] = acc[j][i];
      }
    }
  }
}

// ---------------------------------------------------------------------------
// Fallback fused GEMM (R3 structure, validated) for degraded ws sizes.
// ---------------------------------------------------------------------------
#define RAW_BUF   12288
#define RAW_ARR   4096
#define BF_BASE   24576
#define LDS_TOTAL 26624

template<int NSPLIT, bool USE_XS>
__global__ __launch_bounds__(256, 4)
void vgemm3(const uint16_t* __restrict__ xs,
            const float*    __restrict__ xf,
            const float*    __restrict__ wmu,
            const float*    __restrict__ wlv,
            const float*    __restrict__ weps,
            const float*    __restrict__ biasp,
            const float*    __restrict__ bmu,
            const float*    __restrict__ blv,
            const float*    __restrict__ beps,
            float*          __restrict__ out)
{
  __shared__ __align__(16) uint8_t lds[LDS_TOTAL];

  const int tid = threadIdx.x;
  const int wv  = tid >> 6;
  const int l   = tid & 63;
  const int col_tile = blockIdx.x / NSPLIT;
  const int ks       = blockIdx.x % NSPLIT;
  const int n0  = col_tile * 16;
  const int k0  = ks * (IN_F / NSPLIT);
  const int NT  = (IN_F / NSPLIT) / 64;

  const size_t sgoff = (size_t)(n0 + 4 * wv + (l >> 4)) * IN_F + k0 + ((l & 15) << 2);
  const int cr = tid >> 4;
  const int ci = tid & 15;
  const int bfw = cr * 128 + ((((ci >> 1) ^ (cr & 7)) << 4)) + ((ci & 1) << 3);
  const int br = l & 15;
  const int kb = l >> 4;
  const int bfo0 = br * 128 + ((((0 * 4 + kb)) ^ (br & 7)) << 4);
  const int bfo1 = br * 128 + ((((1 * 4 + kb)) ^ (br & 7)) << 4);
  const int arow0 = wv * 64 + br;

  f32x4 acc[4] = {{0,0,0,0},{0,0,0,0},{0,0,0,0},{0,0,0,0}};

  auto STAGE = [&](int t, int buf) {
    const size_t go = sgoff + (size_t)t * 64;
    uint8_t* base = &lds[0] + buf * RAW_BUF + wv * 1024;
    gload_lds16(wmu  + go, base + 0 * RAW_ARR);
    gload_lds16(wlv  + go, base + 1 * RAW_ARR);
    gload_lds16(weps + go, base + 2 * RAW_ARR);
  };
  auto CVT = [&](int buf) {
    const uint8_t* rb = &lds[0] + buf * RAW_BUF;
    f32x4 m = *(const f32x4*)(rb + 0 * RAW_ARR + tid * 16);
    f32x4 v = *(const f32x4*)(rb + 1 * RAW_ARR + tid * 16);
    f32x4 e = *(const f32x4*)(rb + 2 * RAW_ARR + tid * 16);
    u32x2 o;
    o[0] = pack2bf(fmaf(e[0], exp2f(v[0] * HALF_LOG2E), m[0]),
                   fmaf(e[1], exp2f(v[1] * HALF_LOG2E), m[1]));
    o[1] = pack2bf(fmaf(e[2], exp2f(v[2] * HALF_LOG2E), m[2]),
                   fmaf(e[3], exp2f(v[3] * HALF_LOG2E), m[3]));
    *(u32x2*)(&lds[0] + BF_BASE + bfw) = o;
  };
  auto COMP = [&](int t) {
    const uint8_t* bfb = &lds[0] + BF_BASE;
    bf16x8 b0 = *(const bf16x8*)(bfb + bfo0);
    bf16x8 b1 = *(const bf16x8*)(bfb + bfo1);
    const size_t kb0 = (size_t)k0 + t * 64 + kb * 8;
#pragma unroll
    for (int j = 0; j < 4; ++j) {
      bf16x8 a0, a1;
      if constexpr (USE_XS) {
        const uint16_t* xp = xs + (size_t)(arow0 + 16 * j) * IN_F + kb0;
        a0 = *(const bf16x8*)(xp);
        a1 = *(const bf16x8*)(xp + 32);
      } else {
        const float* xp = xf + (size_t)(arow0 + 16 * j) * IN_F + kb0;
        a0 = cvt8(xp);
        a1 = cvt8(xp + 32);
      }
      acc[j] = MFMA(a0, b0, acc[j]);
      acc[j] = MFMA(a1, b1, acc[j]);
    }
  };

  STAGE(0, 0);
  for (int t = 0; t < NT; ++t) {
    if (t + 1 < NT) STAGE(t + 1, (t + 1) & 1);
    __syncthreads();
    CVT(t & 1);
    __syncthreads();
    COMP(t);
  }

  const int col = n0 + br;
  if constexpr (NSPLIT == 1) {
    float bv;
    if constexpr (USE_XS) bv = biasp[col];
    else bv = fmaf(beps[col], exp2f(blv[col] * HALF_LOG2E), bmu[col]);
#pragma unroll
    for (int j = 0; j < 4; ++j) {
      const int rbase = wv * 64 + j * 16 + kb * 4;
#pragma unroll
      for (int i = 0; i < 4; ++i)
        out[(size_t)(rbase + i) * OUT_F + col] = acc[j][i] + bv;
    }
  } else {
    float* po = out + (size_t)ks * BATCH * OUT_F;
#pragma unroll
    for (int j = 0; j < 4; ++j) {
      const int rbase = wv * 64 + j * 16 + kb * 4;
#pragma unroll
      for (int i = 0; i < 4; ++i)
        po[(size_t)(rbase + i) * OUT_F + col] = acc[j][i];
    }
  }
}

// ---------------------------------------------------------------------------
__global__ __launch_bounds__(256) void reduce_kernel(
    const float* __restrict__ parts,
    const float* __restrict__ bias,
    float* __restrict__ y)
{
  const size_t e = ((size_t)blockIdx.x * 256 + threadIdx.x) * 4;
  f32x4 s = *(const f32x4*)(parts + e);
#pragma unroll
  for (int p = 1; p < KSPLIT; ++p)
    s += *(const f32x4*)(parts + (size_t)p * BATCH * OUT_F + e);
  s += *(const f32x4*)(bias + (e & (OUT_F - 1)));
  *(f32x4*)(y + e) = s;
}

// ---------------------------------------------------------------------------
extern "C" void kernel_launch(void* const* d_in, const int* in_sizes, int n_in,
                              void* d_out, int out_size, void* d_ws, size_t ws_size,
                              hipStream_t stream) {
  const float* x    = (const float*)d_in[0];
  const float* wmu  = (const float*)d_in[1];
  const float* wlv  = (const float*)d_in[2];
  const float* bmu  = (const float*)d_in[3];
  const float* blv  = (const float*)d_in[4];
  const float* weps = (const float*)d_in[5];
  const float* beps = (const float*)d_in[6];
  float* y = (float*)d_out;

  const size_t xs_b   = (size_t)BATCH * IN_F * 2;            // 2 MiB
  const size_t bias_b = (size_t)OUT_F * 4;                   // 16 KiB
  const size_t part_b = (size_t)KSPLIT * BATCH * OUT_F * 4;  // 16 MiB
  const size_t img_b  = (size_t)OUT_F * IN_F * 2;            // 32 MiB

  uint16_t* xsp  = (uint16_t*)d_ws;
  float*    bias = (float*)((char*)d_ws + xs_b);

  if (d_ws && ws_size >= xs_b + bias_b + part_b + img_b) {
    float*   parts = (float*)((char*)d_ws + xs_b + bias_b);
    uint8_t* wimg  = (uint8_t*)d_ws + xs_b + bias_b + part_b;
    prep_kernel<<<528, 256, 0, stream>>>(x, bmu, blv, beps, (u32x4*)d_ws, bias);
    wcvt_kernel<<<8192, 256, 0, stream>>>(wmu, wlv, weps, wimg);
    vgemm_img<KSPLIT><<<(OUT_F / 32) * KSPLIT, 256, 0, stream>>>(xsp, wimg, bias, parts);
    reduce_kernel<<<(BATCH * OUT_F) / (256 * 4), 256, 0, stream>>>(parts, bias, y);
  } else if (d_ws && ws_size >= xs_b + bias_b + img_b) {
    uint8_t* wimg = (uint8_t*)d_ws + xs_b + bias_b;
    prep_kernel<<<528, 256, 0, stream>>>(x, bmu, blv, beps, (u32x4*)d_ws, bias);
    wcvt_kernel<<<8192, 256, 0, stream>>>(wmu, wlv, weps, wimg);
    vgemm_img<1><<<OUT_F / 32, 256, 0, stream>>>(xsp, wimg, bias, y);
  } else if (d_ws && ws_size >= xs_b + bias_b + part_b) {
    float* parts = (float*)((char*)d_ws + xs_b + bias_b);
    prep_kernel<<<528, 256, 0, stream>>>(x, bmu, blv, beps, (u32x4*)d_ws, bias);
    vgemm3<KSPLIT, true><<<(OUT_F / 16) * KSPLIT, 256, 0, stream>>>(
        xsp, nullptr, wmu, wlv, weps, bias, nullptr, nullptr, nullptr, parts);
    reduce_kernel<<<(BATCH * OUT_F) / (256 * 4), 256, 0, stream>>>(parts, bias, y);
  } else if (d_ws && ws_size >= xs_b + bias_b) {
    prep_kernel<<<528, 256, 0, stream>>>(x, bmu, blv, beps, (u32x4*)d_ws, bias);
    vgemm3<1, true><<<OUT_F / 16, 256, 0, stream>>>(
        xsp, nullptr, wmu, wlv, weps, bias, nullptr, nullptr, nullptr, y);
  } else {
    vgemm3<1, false><<<OUT_F / 16, 256, 0, stream>>>(
        nullptr, x, wmu, wlv, weps, nullptr, bmu, blv, beps, y);
  }
}

// Round 5
// 81.567 us; speedup vs baseline: 1.0488x; 1.0488x over previous
//
#include <hip/hip_runtime.h>
#include <stdint.h>
#include <stddef.h>

#define BATCH 256
#define IN_F  4096
#define OUT_F 4096
#define KSPLIT 4

typedef __attribute__((ext_vector_type(8))) short    bf16x8;
typedef __attribute__((ext_vector_type(4))) float    f32x4;
typedef __attribute__((ext_vector_type(2))) uint32_t u32x2;
typedef __attribute__((ext_vector_type(4))) uint32_t u32x4;

#define MFMA(a,b,c) __builtin_amdgcn_mfma_f32_16x16x32_bf16((a),(b),(c),0,0,0)
#define HALF_LOG2E 0.7213475204444817f   // exp(0.5*x) == exp2(x*HALF_LOG2E)

__device__ __forceinline__ uint32_t pack2bf(float a, float b) {
  uint32_t ua = __builtin_bit_cast(uint32_t, a);
  uint32_t ub = __builtin_bit_cast(uint32_t, b);
  ua += 0x7FFFu + ((ua >> 16) & 1u);
  ub += 0x7FFFu + ((ub >> 16) & 1u);
  return (ua >> 16) | (ub & 0xFFFF0000u);
}

__device__ __forceinline__ bf16x8 cvt8(const float* p) {
  f32x4 v0 = *(const f32x4*)p;
  f32x4 v1 = *(const f32x4*)(p + 4);
  union { u32x4 u; bf16x8 h; } r;
  r.u[0] = pack2bf(v0[0], v0[1]); r.u[1] = pack2bf(v0[2], v0[3]);
  r.u[2] = pack2bf(v1[0], v1[1]); r.u[3] = pack2bf(v1[2], v1[3]);
  return r.h;
}

__device__ __forceinline__ void gload_lds16(const void* g, void* l) {
  __builtin_amdgcn_global_load_lds(
      (const __attribute__((address_space(1))) uint32_t*)g,
      (__attribute__((address_space(3))) uint32_t*)l, 16, 0, 0);
}

// ---------------------------------------------------------------------------
// Fused streaming pass (the HBM-bound 192 MB read):
//   W = mu + eps*exp(.5*lv) -> bf16 tile images (swizzle baked in, layout
//   identical to R4's validated one); x -> bf16; bias precompute.
// m13 pattern: every load is lane-contiguous dwordx4 (wave = contiguous 1KB);
// 12 independent loads batched per thread (4 slabs x 3 arrays) for MLP.
// Thread owns 4 consecutive floats per slab; stores 8 B lane-contiguous
// (16B-swizzled groups covered by lane pairs). No LDS, no barriers.
// ---------------------------------------------------------------------------
#define WBLK 4096   // W blocks: 4M chunks / (256 thr * 4 slabs)
#define XBLK 256    // x blocks: 256K chunks / 1024

__global__ __launch_bounds__(256) void wcvt_fused(
    const float* __restrict__ wmu,
    const float* __restrict__ wlv,
    const float* __restrict__ weps,
    const float* __restrict__ x,
    const float* __restrict__ bmu,
    const float* __restrict__ blv,
    const float* __restrict__ beps,
    uint8_t*  __restrict__ wimg,
    uint8_t*  __restrict__ xs,
    float*    __restrict__ bias)
{
  const uint32_t b   = blockIdx.x;
  const uint32_t tid = threadIdx.x;

  if (b < WBLK) {
    // Block converts W row n=b (4096 floats) -> row r of images nt*32+kt.
    const uint32_t c0 = b * 1024u + tid;        // 16B-chunk ids c0 + 256*i
    f32x4 m[4], v[4], e[4];
#pragma unroll
    for (int i = 0; i < 4; ++i) {               // 12 independent 16B loads
      const size_t off = (size_t)(c0 + 256u * i) * 4u;
      m[i] = *(const f32x4*)(wmu + off);
      v[i] = *(const f32x4*)(wlv + off);
      e[i] = *(const f32x4*)(weps + off);
    }
    const uint32_t n  = b;                      // c >> 10 == b for all slabs
    const uint32_t nt = n >> 4, r = n & 15u;
#pragma unroll
    for (int i = 0; i < 4; ++i) {
      const uint32_t c = c0 + 256u * i;
      const uint32_t k = (c & 1023u) << 2;      // element col in row
      u32x2 o;
      o[0] = pack2bf(fmaf(e[i][0], exp2f(v[i][0] * HALF_LOG2E), m[i][0]),
                     fmaf(e[i][1], exp2f(v[i][1] * HALF_LOG2E), m[i][1]));
      o[1] = pack2bf(fmaf(e[i][2], exp2f(v[i][2] * HALF_LOG2E), m[i][2]),
                     fmaf(e[i][3], exp2f(v[i][3] * HALF_LOG2E), m[i][3]));
      const uint32_t kt = k >> 7;
      const uint32_t g  = (k >> 3) & 15u;       // 16B group within 256B row
      const uint32_t h  = (k >> 2) & 1u;        // 8B half within group
      *(u32x2*)(wimg + (((size_t)(nt * 32u + kt)) << 12)
                     + (r << 8) + (((g ^ r) & 15u) << 4) + (h << 3)) = o;
    }
  } else if (b < WBLK + XBLK) {
    const uint32_t c0 = (b - WBLK) * 1024u + tid;
    f32x4 xv[4];
#pragma unroll
    for (int i = 0; i < 4; ++i)
      xv[i] = *(const f32x4*)(x + (size_t)(c0 + 256u * i) * 4u);
#pragma unroll
    for (int i = 0; i < 4; ++i) {
      const size_t off = (size_t)(c0 + 256u * i) * 4u;
      u32x2 o;
      o[0] = pack2bf(xv[i][0], xv[i][1]);
      o[1] = pack2bf(xv[i][2], xv[i][3]);
      *(u32x2*)(xs + (off << 1)) = o;           // byte offset = elem * 2
    }
  } else {
#pragma unroll
    for (int i = 0; i < 16; ++i) {
      const int j = i * 256 + (int)tid;
      bias[j] = fmaf(beps[j], exp2f(blv[j] * HALF_LOG2E), bmu[j]);
    }
  }
}

// ---------------------------------------------------------------------------
// Pass 2: y = xs @ W_bf16^T (+ bias if NSPLIT==1, else fp32 partials).
// (unchanged from R4 — validated, ~9 us)
// ---------------------------------------------------------------------------
template<int NSPLIT>
__global__ __launch_bounds__(256, 2)
void vgemm_img(const uint16_t* __restrict__ xs,
               const uint8_t*  __restrict__ wimg,
               const float*    __restrict__ biasp,
               float*          __restrict__ out)
{
  __shared__ __align__(16) uint8_t lds[16384];   // 2 bufs x 2 images x 4 KB

  const int tid = threadIdx.x;
  const int wv  = tid >> 6;
  const int l   = tid & 63;
  const int cg  = blockIdx.x / NSPLIT;
  const int ks  = blockIdx.x % NSPLIT;
  const int nt0 = cg * 2;
  const int KT0 = ks * (32 / NSPLIT);
  const int NIT = 32 / NSPLIT;

  const int br = l & 15;
  const int kb = l >> 4;
  const int arow0 = wv * 64 + br;

  f32x4 acc0[4] = {{0,0,0,0},{0,0,0,0},{0,0,0,0},{0,0,0,0}};
  f32x4 acc1[4] = {{0,0,0,0},{0,0,0,0},{0,0,0,0},{0,0,0,0}};

  auto STAGE = [&](int t, int buf) {
    const int kt = KT0 + t;
#pragma unroll
    for (int j = 0; j < 2; ++j) {
      const int ch = wv * 2 + j;
      const int i  = ch >> 2;
      const int q  = ch & 3;
      const uint8_t* src = wimg + (((size_t)((nt0 + i) * 32 + kt)) << 12)
                                + q * 1024 + l * 16;
      gload_lds16(src, &lds[0] + buf * 8192 + i * 4096 + q * 1024 + l * 16);
    }
  };

  auto COMP = [&](int t, int buf) {
    const uint8_t* B = &lds[0] + buf * 8192;
#pragma unroll
    for (int s = 0; s < 4; ++s) {
      const int swz = br * 256 + ((((s * 4 + kb) ^ br) & 15) << 4);
      bf16x8 b0 = *(const bf16x8*)(B + swz);
      bf16x8 b1 = *(const bf16x8*)(B + 4096 + swz);
      const size_t kk = (size_t)(KT0 + t) * 128 + s * 32 + kb * 8;
#pragma unroll
      for (int j = 0; j < 4; ++j) {
        bf16x8 a = *(const bf16x8*)(xs + (size_t)(arow0 + 16 * j) * IN_F + kk);
        acc0[j] = MFMA(a, b0, acc0[j]);
        acc1[j] = MFMA(a, b1, acc1[j]);
      }
    }
  };

  STAGE(0, 0);
  for (int t = 0; t < NIT; ++t) {
    if (t + 1 < NIT) STAGE(t + 1, (t + 1) & 1);
    __syncthreads();
    COMP(t, t & 1);
    __syncthreads();
  }

#pragma unroll
  for (int img = 0; img < 2; ++img) {
    const f32x4* acc = img ? acc1 : acc0;
    const int col = cg * 32 + img * 16 + br;
    if constexpr (NSPLIT == 1) {
      const float bv = biasp[col];
#pragma unroll
      for (int j = 0; j < 4; ++j) {
        const int rbase = wv * 64 + j * 16 + kb * 4;
#pragma unroll
        for (int i = 0; i < 4; ++i)
          out[(size_t)(rbase + i) * OUT_F + col] = acc[j][i] + bv;
      }
    } else {
      float* po = out + (size_t)ks * BATCH * OUT_F;
#pragma unroll
      for (int j = 0; j < 4; ++j) {
        const int rbase = wv * 64 + j * 16 + kb * 4;
#pragma unroll
        for (int i = 0; i < 4; ++i)
          po[(size_t)(rbase + i) * OUT_F + col] = acc[j][i];
      }
    }
  }
}

// ---------------------------------------------------------------------------
// Fallback prep + fused GEMM (R3 structure) for degraded ws sizes.
// ---------------------------------------------------------------------------
__global__ __launch_bounds__(256) void prep_kernel(
    const float* __restrict__ x,
    const float* __restrict__ bmu,
    const float* __restrict__ blv,
    const float* __restrict__ beps,
    u32x4* __restrict__ xs4,
    float* __restrict__ bias)
{
  const uint32_t b = blockIdx.x;
  if (b < 512u) {
    const uint32_t c = b * 256u + threadIdx.x;
    const float* p = x + (size_t)c * 8u;
    f32x4 v0 = *(const f32x4*)p;
    f32x4 v1 = *(const f32x4*)(p + 4);
    u32x4 o;
    o[0] = pack2bf(v0[0], v0[1]); o[1] = pack2bf(v0[2], v0[3]);
    o[2] = pack2bf(v1[0], v1[1]); o[3] = pack2bf(v1[2], v1[3]);
    xs4[c] = o;
  } else {
    const uint32_t i = (b - 512u) * 256u + threadIdx.x;
    bias[i] = fmaf(beps[i], exp2f(blv[i] * HALF_LOG2E), bmu[i]);
  }
}

#define RAW_BUF   12288
#define RAW_ARR   4096
#define BF_BASE   24576
#define LDS_TOTAL 26624

template<int NSPLIT, bool USE_XS>
__global__ __launch_bounds__(256, 4)
void vgemm3(const uint16_t* __restrict__ xs,
            const float*    __restrict__ xf,
            const float*    __restrict__ wmu,
            const float*    __restrict__ wlv,
            const float*    __restrict__ weps,
            const float*    __restrict__ biasp,
            const float*    __restrict__ bmu,
            const float*    __restrict__ blv,
            const float*    __restrict__ beps,
            float*          __restrict__ out)
{
  __shared__ __align__(16) uint8_t lds[LDS_TOTAL];

  const int tid = threadIdx.x;
  const int wv  = tid >> 6;
  const int l   = tid & 63;
  const int col_tile = blockIdx.x / NSPLIT;
  const int ks       = blockIdx.x % NSPLIT;
  const int n0  = col_tile * 16;
  const int k0  = ks * (IN_F / NSPLIT);
  const int NT  = (IN_F / NSPLIT) / 64;

  const size_t sgoff = (size_t)(n0 + 4 * wv + (l >> 4)) * IN_F + k0 + ((l & 15) << 2);
  const int cr = tid >> 4;
  const int ci = tid & 15;
  const int bfw = cr * 128 + ((((ci >> 1) ^ (cr & 7)) << 4)) + ((ci & 1) << 3);
  const int br = l & 15;
  const int kb = l >> 4;
  const int bfo0 = br * 128 + ((((0 * 4 + kb)) ^ (br & 7)) << 4);
  const int bfo1 = br * 128 + ((((1 * 4 + kb)) ^ (br & 7)) << 4);
  const int arow0 = wv * 64 + br;

  f32x4 acc[4] = {{0,0,0,0},{0,0,0,0},{0,0,0,0},{0,0,0,0}};

  auto STAGE = [&](int t, int buf) {
    const size_t go = sgoff + (size_t)t * 64;
    uint8_t* base = &lds[0] + buf * RAW_BUF + wv * 1024;
    gload_lds16(wmu  + go, base + 0 * RAW_ARR);
    gload_lds16(wlv  + go, base + 1 * RAW_ARR);
    gload_lds16(weps + go, base + 2 * RAW_ARR);
  };
  auto CVT = [&](int buf) {
    const uint8_t* rb = &lds[0] + buf * RAW_BUF;
    f32x4 m = *(const f32x4*)(rb + 0 * RAW_ARR + tid * 16);
    f32x4 v = *(const f32x4*)(rb + 1 * RAW_ARR + tid * 16);
    f32x4 e = *(const f32x4*)(rb + 2 * RAW_ARR + tid * 16);
    u32x2 o;
    o[0] = pack2bf(fmaf(e[0], exp2f(v[0] * HALF_LOG2E), m[0]),
                   fmaf(e[1], exp2f(v[1] * HALF_LOG2E), m[1]));
    o[1] = pack2bf(fmaf(e[2], exp2f(v[2] * HALF_LOG2E), m[2]),
                   fmaf(e[3], exp2f(v[3] * HALF_LOG2E), m[3]));
    *(u32x2*)(&lds[0] + BF_BASE + bfw) = o;
  };
  auto COMP = [&](int t) {
    const uint8_t* bfb = &lds[0] + BF_BASE;
    bf16x8 b0 = *(const bf16x8*)(bfb + bfo0);
    bf16x8 b1 = *(const bf16x8*)(bfb + bfo1);
    const size_t kb0 = (size_t)k0 + t * 64 + kb * 8;
#pragma unroll
    for (int j = 0; j < 4; ++j) {
      bf16x8 a0, a1;
      if constexpr (USE_XS) {
        const uint16_t* xp = xs + (size_t)(arow0 + 16 * j) * IN_F + kb0;
        a0 = *(const bf16x8*)(xp);
        a1 = *(const bf16x8*)(xp + 32);
      } else {
        const float* xp = xf + (size_t)(arow0 + 16 * j) * IN_F + kb0;
        a0 = cvt8(xp);
        a1 = cvt8(xp + 32);
      }
      acc[j] = MFMA(a0, b0, acc[j]);
      acc[j] = MFMA(a1, b1, acc[j]);
    }
  };

  STAGE(0, 0);
  for (int t = 0; t < NT; ++t) {
    if (t + 1 < NT) STAGE(t + 1, (t + 1) & 1);
    __syncthreads();
    CVT(t & 1);
    __syncthreads();
    COMP(t);
  }

  const int col = n0 + br;
  if constexpr (NSPLIT == 1) {
    float bv;
    if constexpr (USE_XS) bv = biasp[col];
    else bv = fmaf(beps[col], exp2f(blv[col] * HALF_LOG2E), bmu[col]);
#pragma unroll
    for (int j = 0; j < 4; ++j) {
      const int rbase = wv * 64 + j * 16 + kb * 4;
#pragma unroll
      for (int i = 0; i < 4; ++i)
        out[(size_t)(rbase + i) * OUT_F + col] = acc[j][i] + bv;
    }
  } else {
    float* po = out + (size_t)ks * BATCH * OUT_F;
#pragma unroll
    for (int j = 0; j < 4; ++j) {
      const int rbase = wv * 64 + j * 16 + kb * 4;
#pragma unroll
      for (int i = 0; i < 4; ++i)
        po[(size_t)(rbase + i) * OUT_F + col] = acc[j][i];
    }
  }
}

// ---------------------------------------------------------------------------
__global__ __launch_bounds__(256) void reduce_kernel(
    const float* __restrict__ parts,
    const float* __restrict__ bias,
    float* __restrict__ y)
{
  const size_t e = ((size_t)blockIdx.x * 256 + threadIdx.x) * 4;
  f32x4 s = *(const f32x4*)(parts + e);
#pragma unroll
  for (int p = 1; p < KSPLIT; ++p)
    s += *(const f32x4*)(parts + (size_t)p * BATCH * OUT_F + e);
  s += *(const f32x4*)(bias + (e & (OUT_F - 1)));
  *(f32x4*)(y + e) = s;
}

// ---------------------------------------------------------------------------
extern "C" void kernel_launch(void* const* d_in, const int* in_sizes, int n_in,
                              void* d_out, int out_size, void* d_ws, size_t ws_size,
                              hipStream_t stream) {
  const float* x    = (const float*)d_in[0];
  const float* wmu  = (const float*)d_in[1];
  const float* wlv  = (const float*)d_in[2];
  const float* bmu  = (const float*)d_in[3];
  const float* blv  = (const float*)d_in[4];
  const float* weps = (const float*)d_in[5];
  const float* beps = (const float*)d_in[6];
  float* y = (float*)d_out;

  const size_t xs_b   = (size_t)BATCH * IN_F * 2;            // 2 MiB
  const size_t bias_b = (size_t)OUT_F * 4;                   // 16 KiB
  const size_t part_b = (size_t)KSPLIT * BATCH * OUT_F * 4;  // 16 MiB
  const size_t img_b  = (size_t)OUT_F * IN_F * 2;            // 32 MiB

  uint16_t* xsp  = (uint16_t*)d_ws;
  float*    bias = (float*)((char*)d_ws + xs_b);

  if (d_ws && ws_size >= xs_b + bias_b + part_b + img_b) {
    float*   parts = (float*)((char*)d_ws + xs_b + bias_b);
    uint8_t* wimg  = (uint8_t*)d_ws + xs_b + bias_b + part_b;
    wcvt_fused<<<WBLK + XBLK + 1, 256, 0, stream>>>(
        wmu, wlv, weps, x, bmu, blv, beps, wimg, (uint8_t*)xsp, bias);
    vgemm_img<KSPLIT><<<(OUT_F / 32) * KSPLIT, 256, 0, stream>>>(xsp, wimg, bias, parts);
    reduce_kernel<<<(BATCH * OUT_F) / (256 * 4), 256, 0, stream>>>(parts, bias, y);
  } else if (d_ws && ws_size >= xs_b + bias_b + img_b) {
    uint8_t* wimg = (uint8_t*)d_ws + xs_b + bias_b;
    wcvt_fused<<<WBLK + XBLK + 1, 256, 0, stream>>>(
        wmu, wlv, weps, x, bmu, blv, beps, wimg, (uint8_t*)xsp, bias);
    vgemm_img<1><<<OUT_F / 32, 256, 0, stream>>>(xsp, wimg, bias, y);
  } else if (d_ws && ws_size >= xs_b + bias_b + part_b) {
    float* parts = (float*)((char*)d_ws + xs_b + bias_b);
    prep_kernel<<<528, 256, 0, stream>>>(x, bmu, blv, beps, (u32x4*)d_ws, bias);
    vgemm3<KSPLIT, true><<<(OUT_F / 16) * KSPLIT, 256, 0, stream>>>(
        xsp, nullptr, wmu, wlv, weps, bias, nullptr, nullptr, nullptr, parts);
    reduce_kernel<<<(BATCH * OUT_F) / (256 * 4), 256, 0, stream>>>(parts, bias, y);
  } else if (d_ws && ws_size >= xs_b + bias_b) {
    prep_kernel<<<528, 256, 0, stream>>>(x, bmu, blv, beps, (u32x4*)d_ws, bias);
    vgemm3<1, true><<<OUT_F / 16, 256, 0, stream>>>(
        xsp, nullptr, wmu, wlv, weps, bias, nullptr, nullptr, nullptr, y);
  } else {
    vgemm3<1, false><<<OUT_F / 16, 256, 0, stream>>>(
        nullptr, x, wmu, wlv, weps, nullptr, bmu, blv, beps, y);
  }
}